// Round 5
// baseline (161.218 us; speedup 1.0000x reference)
//
#include <hip/hip_runtime.h>
#include <math.h>

// Problem constants (B=2, N=M=2048, d_model=1024, m_bits=32, d_head=64)
#define DM 1024
#define NB 2048
#define MBITS 32
#define DH 64

typedef __attribute__((ext_vector_type(4))) float floatx4;
typedef __attribute__((ext_vector_type(8))) short shortx8;

__device__ __forceinline__ unsigned short f32_to_bf16(float f) {
    union { float f; unsigned u; } v; v.f = f;
    unsigned r = v.u + 0x7FFF + ((v.u >> 16) & 1);   // RNE
    return (unsigned short)(r >> 16);
}

// hi/lo truncation split of two f32 -> packed bf16x2 (el0 low, el1 high)
__device__ __forceinline__ void split2(float x0, float x1, unsigned& hp, unsigned& lp) {
    union { float f; unsigned u; } a, b; a.f = x0; b.f = x1;
    unsigned h0 = a.u & 0xFFFF0000u, h1 = b.u & 0xFFFF0000u;
    union { unsigned u; float f; } hf0, hf1; hf0.u = h0; hf1.u = h1;
    union { float f; unsigned u; } c, d;
    c.f = x0 - hf0.f;   // exact
    d.f = x1 - hf1.f;
    hp = (h0 >> 16) | h1;
    lp = (c.u >> 16) | (d.u & 0xFFFF0000u);
}

// ---------------------------------------------------------------------------
// W prep: pack Wq/Wk/Wv into MFMA B-frag order, bf16 hi/lo. (verified r3/r4)
// Pair p: Wf[p*1024 + lane*8 + j] = hi, [+512] = lo.
// B-frag: lane l holds B[k = kc32*32 + (l>>4)*8 + j][col = ct*16 + (l&15)].
// ---------------------------------------------------------------------------
__global__ __launch_bounds__(256) void wprep_kernel(
    const float* __restrict__ Wq, const float* __restrict__ Wk,
    const float* __restrict__ Wv, unsigned short* __restrict__ Wf)
{
    int wv = blockIdx.x * 4 + (threadIdx.x >> 6);
    int l  = threadIdx.x & 63;
    const float* W; int C, kc32, ct;
    if (wv < 64)       { W = Wq; C = 32; kc32 = wv >> 1;  ct = wv & 1; }
    else if (wv < 128) { W = Wk; C = 32; int z = wv - 64;  kc32 = z >> 1; ct = z & 1; }
    else               { W = Wv; C = 64; int z = wv - 128; kc32 = z >> 2; ct = z & 3; }
    int k0 = kc32 * 32 + (l >> 4) * 8;
    int c  = ct * 16 + (l & 15);
    float x[8];
    #pragma unroll
    for (int j = 0; j < 8; ++j) x[j] = W[(size_t)(k0 + j) * C + c];
    unsigned hp[4], lp[4];
    #pragma unroll
    for (int j2 = 0; j2 < 4; ++j2) split2(x[2 * j2], x[2 * j2 + 1], hp[j2], lp[j2]);
    uint4 hv; hv.x = hp[0]; hv.y = hp[1]; hv.z = hp[2]; hv.w = hp[3];
    uint4 lv; lv.x = lp[0]; lv.y = lp[1]; lv.z = lp[2]; lv.w = lp[3];
    *(uint4*)&Wf[(size_t)wv * 1024 + l * 8]       = hv;
    *(uint4*)&Wf[(size_t)wv * 1024 + 512 + l * 8] = lv;
}

// ---------------------------------------------------------------------------
// Projections: register-direct A-frags, split-K x4 across waves, explicit
// X prefetch double-buffer. grid 768 x 256 (job = blockIdx.x>>8).
//  job 0: Qt = Q@Wq   job 1: Kt = K@Wk   job 2: VpT bf16 [b][h][j]
// ---------------------------------------------------------------------------
__global__ __launch_bounds__(256) void proj_mfma2_kernel(
    const float* __restrict__ Q, const float* __restrict__ K, const float* __restrict__ V,
    const unsigned short* __restrict__ Wf,
    float* __restrict__ Qt, float* __restrict__ Kt, unsigned short* __restrict__ VpT)
{
    __shared__ float red[4][64][16];   // [wave][lane][ct*4+r] = 16 KB

    int gb = blockIdx.x;
    int job = gb >> 8, tile = gb & 255;
    int r0 = tile * 16;
    const float* X = (job == 0) ? Q : (job == 1) ? K : V;
    int ntct  = (job == 2) ? 4 : 2;
    int pbase = job << 6;
    int t = threadIdx.x, w = t >> 6, l = t & 63;
    int lrow = l & 15, lq = l >> 4;

    const float* xrow = &X[(size_t)(r0 + lrow) * DM + w * 256 + lq * 8];

    floatx4 acc[4];
    #pragma unroll
    for (int i = 0; i < 4; ++i) acc[i] = (floatx4){0.f, 0.f, 0.f, 0.f};

    floatx4 g0 = *(const floatx4*)(xrow);
    floatx4 g1 = *(const floatx4*)(xrow + 4);

    #pragma unroll
    for (int s = 0; s < 8; ++s) {
        floatx4 n0, n1;
        if (s < 7) {
            n0 = *(const floatx4*)(xrow + (s + 1) * 32);
            n1 = *(const floatx4*)(xrow + (s + 1) * 32 + 4);
        }
        union { unsigned u[4]; shortx8 v; } ahi, alo;
        split2(g0.x, g0.y, ahi.u[0], alo.u[0]);
        split2(g0.z, g0.w, ahi.u[1], alo.u[1]);
        split2(g1.x, g1.y, ahi.u[2], alo.u[2]);
        split2(g1.z, g1.w, ahi.u[3], alo.u[3]);
        int kc32 = w * 8 + s;
        #pragma unroll
        for (int ct = 0; ct < 4; ++ct) {
            if (ct >= ntct) break;
            int p = pbase + kc32 * ntct + ct;
            const unsigned short* wp = &Wf[(size_t)p * 1024 + l * 8];
            shortx8 bhi = *(const shortx8*)wp;
            shortx8 blo = *(const shortx8*)(wp + 512);
            acc[ct] = __builtin_amdgcn_mfma_f32_16x16x32_bf16(ahi.v, bhi, acc[ct], 0, 0, 0);
            acc[ct] = __builtin_amdgcn_mfma_f32_16x16x32_bf16(ahi.v, blo, acc[ct], 0, 0, 0);
            acc[ct] = __builtin_amdgcn_mfma_f32_16x16x32_bf16(alo.v, bhi, acc[ct], 0, 0, 0);
        }
        g0 = n0; g1 = n1;
    }

    #pragma unroll
    for (int ct = 0; ct < 4; ++ct) {
        if (ct >= ntct) break;
        #pragma unroll
        for (int r = 0; r < 4; ++r) red[w][l][ct * 4 + r] = acc[ct][r];
    }
    __syncthreads();

    // wave w sums accumulator register r = w across the 4 k-quarters.
    int row = r0 + lq * 4 + w;
    if (job < 2) {
        float* Y = (job == 0) ? Qt : Kt;
        #pragma unroll
        for (int ct = 0; ct < 2; ++ct) {
            float v = red[0][l][ct * 4 + w] + red[1][l][ct * 4 + w]
                    + red[2][l][ct * 4 + w] + red[3][l][ct * 4 + w];
            Y[(size_t)row * MBITS + ct * 16 + lrow] = v;
        }
    } else {
        int b = row >> 11, j = row & 2047;
        #pragma unroll
        for (int ct = 0; ct < 4; ++ct) {
            float v = red[0][l][ct * 4 + w] + red[1][l][ct * 4 + w]
                    + red[2][l][ct * 4 + w] + red[3][l][ct * 4 + w];
            VpT[(size_t)b * (DH * NB) + (size_t)(ct * 16 + lrow) * NB + j] = f32_to_bf16(v);
        }
    }
}

// ---------------------------------------------------------------------------
// Pass 1: tropical min-plus -> per-(row, j-chunk) partial expsums only.
// grid (128, 8, 2) x 256. Block = 16 rows x 256 j, thread 4i x 4j. ~39 KB LDS.
// ---------------------------------------------------------------------------
__global__ __launch_bounds__(256) void trop_sum_kernel(
    const float* __restrict__ Qt, const float* __restrict__ Kt,
    const float* __restrict__ temp, float* __restrict__ partial)
{
    __shared__ float Qs[16][36];
    __shared__ float Ks[256][36];

    int b  = blockIdx.z;
    int jc = blockIdx.y;
    int i0 = blockIdx.x * 16;
    int t  = threadIdx.x;
    int w  = t >> 6, l = t & 63;

    if (t < 128) {
        int row = t >> 3, k4 = t & 7;
        *(floatx4*)&Qs[row][k4 * 4] =
            *(const floatx4*)&Qt[(size_t)(b * NB + i0 + row) * MBITS + k4 * 4];
    }
    #pragma unroll
    for (int u = 0; u < 8; ++u) {
        int flat4 = u * 256 + t;
        int row = flat4 >> 3, k4 = flat4 & 7;
        *(floatx4*)&Ks[row][k4 * 4] =
            *(const floatx4*)&Kt[(size_t)(b * NB + jc * 256 + row) * MBITS + k4 * 4];
    }
    float tv = temp[0];
    float c2 = -(1.0f / log1pf(__expf(tv))) * 1.44269504088896340736f;
    __syncthreads();

    float m[4][4];
    #pragma unroll
    for (int ii = 0; ii < 4; ++ii)
        #pragma unroll
        for (int jj = 0; jj < 4; ++jj) m[ii][jj] = 1e30f;

    #pragma unroll
    for (int k4 = 0; k4 < 8; ++k4) {
        floatx4 q[4], kk[4];
        #pragma unroll
        for (int ii = 0; ii < 4; ++ii) q[ii] = *(const floatx4*)&Qs[w + 4 * ii][k4 * 4];
        #pragma unroll
        for (int jj = 0; jj < 4; ++jj) kk[jj] = *(const floatx4*)&Ks[l + 64 * jj][k4 * 4];
        #pragma unroll
        for (int ii = 0; ii < 4; ++ii)
            #pragma unroll
            for (int jj = 0; jj < 4; ++jj) {
                float a0 = q[ii].x + kk[jj].x;
                float a1 = q[ii].y + kk[jj].y;
                float a2 = q[ii].z + kk[jj].z;
                float a3 = q[ii].w + kk[jj].w;
                m[ii][jj] = fminf(fminf(m[ii][jj], fminf(a0, a1)), fminf(a2, a3));
            }
    }

    #pragma unroll
    for (int ii = 0; ii < 4; ++ii) {
        float s = exp2f(c2 * m[ii][0]) + exp2f(c2 * m[ii][1])
                + exp2f(c2 * m[ii][2]) + exp2f(c2 * m[ii][3]);
        #pragma unroll
        for (int off = 1; off < 64; off <<= 1) s += __shfl_xor(s, off, 64);
        if (l == 0) partial[((size_t)b * NB + i0 + w + 4 * ii) * 8 + jc] = s;
    }
}

// ---------------------------------------------------------------------------
// Pass 2 (fused): recompute tropical, write normalized attn, MFMA -> out.
// grid (128, 8, 2) x 256. B-frags read directly from global VpT (L2-resident).
// LDS ~48 KB -> 3 blocks/CU.
// ---------------------------------------------------------------------------
__global__ __launch_bounds__(256) void trop_fused_kernel(
    const float* __restrict__ Qt, const float* __restrict__ Kt,
    const unsigned short* __restrict__ VpT,
    const float* __restrict__ temp, const float* __restrict__ partial,
    float* __restrict__ outp, float* __restrict__ attn)
{
    __shared__ float Qs[16][36];
    __shared__ float Ks[256][36];
    __shared__ unsigned short Es[16][264];   // unnormalized e, bf16 (A-operand)
    __shared__ float inv_s[16];

    int b  = blockIdx.z;
    int jc = blockIdx.y;
    int i0 = blockIdx.x * 16;
    int t  = threadIdx.x;
    int w  = t >> 6, l = t & 63;

    if (t < 128) {
        int row = t >> 3, k4 = t & 7;
        *(floatx4*)&Qs[row][k4 * 4] =
            *(const floatx4*)&Qt[(size_t)(b * NB + i0 + row) * MBITS + k4 * 4];
    }
    #pragma unroll
    for (int u = 0; u < 8; ++u) {
        int flat4 = u * 256 + t;
        int row = flat4 >> 3, k4 = flat4 & 7;
        *(floatx4*)&Ks[row][k4 * 4] =
            *(const floatx4*)&Kt[(size_t)(b * NB + jc * 256 + row) * MBITS + k4 * 4];
    }
    if (t < 16) {
        float s = 0.f;
        #pragma unroll
        for (int p = 0; p < 8; ++p) s += partial[((size_t)b * NB + i0 + t) * 8 + p];
        inv_s[t] = 1.0f / s;
    }
    float tv = temp[0];
    float c2 = -(1.0f / log1pf(__expf(tv))) * 1.44269504088896340736f;
    __syncthreads();

    float m[4][4];
    #pragma unroll
    for (int ii = 0; ii < 4; ++ii)
        #pragma unroll
        for (int jj = 0; jj < 4; ++jj) m[ii][jj] = 1e30f;

    #pragma unroll
    for (int k4 = 0; k4 < 8; ++k4) {
        floatx4 q[4], kk[4];
        #pragma unroll
        for (int ii = 0; ii < 4; ++ii) q[ii] = *(const floatx4*)&Qs[w + 4 * ii][k4 * 4];
        #pragma unroll
        for (int jj = 0; jj < 4; ++jj) kk[jj] = *(const floatx4*)&Ks[l + 64 * jj][k4 * 4];
        #pragma unroll
        for (int ii = 0; ii < 4; ++ii)
            #pragma unroll
            for (int jj = 0; jj < 4; ++jj) {
                float a0 = q[ii].x + kk[jj].x;
                float a1 = q[ii].y + kk[jj].y;
                float a2 = q[ii].z + kk[jj].z;
                float a3 = q[ii].w + kk[jj].w;
                m[ii][jj] = fminf(fminf(m[ii][jj], fminf(a0, a1)), fminf(a2, a3));
            }
    }

    // e = exp2(c2*m): write normalized attn (coalesced), stage bf16 e in LDS
    #pragma unroll
    for (int ii = 0; ii < 4; ++ii) {
        int i = w + 4 * ii;
        float iv = inv_s[i];
        #pragma unroll
        for (int jj = 0; jj < 4; ++jj) {
            int j = l + 64 * jj;
            float e = exp2f(c2 * m[ii][jj]);
            attn[(size_t)(b * NB + i0 + i) * 2048 + jc * 256 + j] = e * iv;
            Es[i][j] = f32_to_bf16(e);
        }
    }
    __syncthreads();

    // out += Es (A) x VpT-frags (B, direct from global). Wave w: h-block w*16.
    const unsigned short* vb =
        &VpT[(size_t)b * (DH * NB) + (size_t)(w * 16 + (l & 15)) * NB
             + jc * 256 + (l >> 4) * 8];
    floatx4 acc = {0.f, 0.f, 0.f, 0.f};
    #pragma unroll
    for (int kk = 0; kk < 8; ++kk) {
        int mrow = l & 15, q4 = l >> 4;
        shortx8 a  = *(const shortx8*)&Es[mrow][kk * 32 + q4 * 8];
        shortx8 bf = *(const shortx8*)(vb + kk * 32);
        acc = __builtin_amdgcn_mfma_f32_16x16x32_bf16(a, bf, acc, 0, 0, 0);
    }

    // C/D: col=lane&15 (h), row=(lane>>4)*4+reg (i)
    #pragma unroll
    for (int r = 0; r < 4; ++r) {
        int irow = (l >> 4) * 4 + r;
        atomicAdd(&outp[(size_t)(b * NB + i0 + irow) * DH + w * 16 + (l & 15)],
                  acc[r] * inv_s[irow]);
    }
}

// ---------------------------------------------------------------------------
extern "C" void kernel_launch(void* const* d_in, const int* in_sizes, int n_in,
                              void* d_out, int out_size, void* d_ws, size_t ws_size,
                              hipStream_t stream) {
    (void)in_sizes; (void)n_in; (void)out_size; (void)ws_size;
    const float* Q    = (const float*)d_in[0];
    const float* K    = (const float*)d_in[1];
    const float* V    = (const float*)d_in[2];
    const float* Wq   = (const float*)d_in[3];
    const float* Wk   = (const float*)d_in[4];
    const float* Wv   = (const float*)d_in[5];
    const float* temp = (const float*)d_in[6];

    float* outp = (float*)d_out;                 // [2][2048][64]
    float* attn = outp + 2 * 2048 * 64;          // [2][2048][2048]

    char* ws = (char*)d_ws;
    float*          Qt      = (float*)(ws);                       // 512 KB
    float*          Kt      = (float*)(ws + 524288);              // 512 KB
    float*          partial = (float*)(ws + 1048576);             // 128 KB
    unsigned short* Wf      = (unsigned short*)(ws + 1179648);    // 512 KB
    unsigned short* VpT     = (unsigned short*)(ws + 1703936);    // 512 KB

    hipMemsetAsync(d_out, 0, 262144 * sizeof(float), stream);     // out accumulators

    wprep_kernel<<<64, 256, 0, stream>>>(Wq, Wk, Wv, Wf);
    proj_mfma2_kernel<<<768, 256, 0, stream>>>(Q, K, V, Wf, Qt, Kt, VpT);
    trop_sum_kernel<<<dim3(128, 8, 2), 256, 0, stream>>>(Qt, Kt, temp, partial);
    trop_fused_kernel<<<dim3(128, 8, 2), 256, 0, stream>>>(
        Qt, Kt, VpT, temp, partial, outp, attn);
}

// Round 6
// 155.945 us; speedup vs baseline: 1.0338x; 1.0338x over previous
//
#include <hip/hip_runtime.h>
#include <math.h>

// Problem constants (B=2, N=M=2048, d_model=1024, m_bits=32, d_head=64)
#define DM 1024
#define NB 2048
#define MBITS 32
#define DH 64

typedef __attribute__((ext_vector_type(4))) float floatx4;
typedef __attribute__((ext_vector_type(8))) short shortx8;

__device__ __forceinline__ unsigned short f32_to_bf16(float f) {
    union { float f; unsigned u; } v; v.f = f;
    unsigned r = v.u + 0x7FFF + ((v.u >> 16) & 1);   // RNE
    return (unsigned short)(r >> 16);
}

// hi/lo truncation split of two f32 -> packed bf16x2 (el0 low, el1 high)
__device__ __forceinline__ void split2(float x0, float x1, unsigned& hp, unsigned& lp) {
    union { float f; unsigned u; } a, b; a.f = x0; b.f = x1;
    unsigned h0 = a.u & 0xFFFF0000u, h1 = b.u & 0xFFFF0000u;
    union { unsigned u; float f; } hf0, hf1; hf0.u = h0; hf1.u = h1;
    union { float f; unsigned u; } c, d;
    c.f = x0 - hf0.f;   // exact
    d.f = x1 - hf1.f;
    hp = (h0 >> 16) | h1;
    lp = (c.u >> 16) | (d.u & 0xFFFF0000u);
}

// ---------------------------------------------------------------------------
// W prep: pack Wq/Wk/Wv into MFMA B-frag order, bf16 hi/lo. (verified r3-r5)
// Pair p: Wf[p*1024 + lane*8 + j] = hi, [+512] = lo.
// B-frag: lane l holds B[k = kc32*32 + (l>>4)*8 + j][col = ct*16 + (l&15)].
// ---------------------------------------------------------------------------
__global__ __launch_bounds__(256) void wprep_kernel(
    const float* __restrict__ Wq, const float* __restrict__ Wk,
    const float* __restrict__ Wv, unsigned short* __restrict__ Wf)
{
    int wv = blockIdx.x * 4 + (threadIdx.x >> 6);
    int l  = threadIdx.x & 63;
    const float* W; int C, kc32, ct;
    if (wv < 64)       { W = Wq; C = 32; kc32 = wv >> 1;  ct = wv & 1; }
    else if (wv < 128) { W = Wk; C = 32; int z = wv - 64;  kc32 = z >> 1; ct = z & 1; }
    else               { W = Wv; C = 64; int z = wv - 128; kc32 = z >> 2; ct = z & 3; }
    int k0 = kc32 * 32 + (l >> 4) * 8;
    int c  = ct * 16 + (l & 15);
    float x[8];
    #pragma unroll
    for (int j = 0; j < 8; ++j) x[j] = W[(size_t)(k0 + j) * C + c];
    unsigned hp[4], lp[4];
    #pragma unroll
    for (int j2 = 0; j2 < 4; ++j2) split2(x[2 * j2], x[2 * j2 + 1], hp[j2], lp[j2]);
    uint4 hv; hv.x = hp[0]; hv.y = hp[1]; hv.z = hp[2]; hv.w = hp[3];
    uint4 lv; lv.x = lp[0]; lv.y = lp[1]; lv.z = lp[2]; lv.w = lp[3];
    *(uint4*)&Wf[(size_t)wv * 1024 + l * 8]       = hv;
    *(uint4*)&Wf[(size_t)wv * 1024 + 512 + l * 8] = lv;
}

// ---------------------------------------------------------------------------
// Projection core: NTCT compile-time (2 for Q/K, 4 for V).
// ---------------------------------------------------------------------------
template <int NTCT>
__device__ __forceinline__ void proj_core(
    const float* xrow, const unsigned short* __restrict__ Wf,
    int pbase, int kc32base, int l, floatx4 acc[4])
{
    floatx4 g0 = *(const floatx4*)(xrow);
    floatx4 g1 = *(const floatx4*)(xrow + 4);
    #pragma unroll
    for (int s = 0; s < 4; ++s) {
        floatx4 n0, n1;
        if (s < 3) {
            n0 = *(const floatx4*)(xrow + (s + 1) * 32);
            n1 = *(const floatx4*)(xrow + (s + 1) * 32 + 4);
        }
        union { unsigned u[4]; shortx8 v; } ahi, alo;
        split2(g0.x, g0.y, ahi.u[0], alo.u[0]);
        split2(g0.z, g0.w, ahi.u[1], alo.u[1]);
        split2(g1.x, g1.y, ahi.u[2], alo.u[2]);
        split2(g1.z, g1.w, ahi.u[3], alo.u[3]);
        int kc32 = kc32base + s;
        #pragma unroll
        for (int ct = 0; ct < NTCT; ++ct) {
            int p = pbase + kc32 * NTCT + ct;
            const unsigned short* wp = &Wf[(size_t)p * 1024 + l * 8];
            shortx8 bhi = *(const shortx8*)wp;
            shortx8 blo = *(const shortx8*)(wp + 512);
            acc[ct] = __builtin_amdgcn_mfma_f32_16x16x32_bf16(ahi.v, bhi, acc[ct], 0, 0, 0);
            acc[ct] = __builtin_amdgcn_mfma_f32_16x16x32_bf16(ahi.v, blo, acc[ct], 0, 0, 0);
            acc[ct] = __builtin_amdgcn_mfma_f32_16x16x32_bf16(alo.v, bhi, acc[ct], 0, 0, 0);
        }
        g0 = n0; g1 = n1;
    }
}

// ---------------------------------------------------------------------------
// Projections: 512-thread blocks, split-K x8 across the 8 waves (wave w owns
// k in [w*128, w*128+128)), LDS reduce with +1-padded stride (conflict-free).
// grid 768 x 512 (job = blockIdx.x>>8).
//  job 0: Qt = Q@Wq   job 1: Kt = K@Wk   job 2: VpT bf16 [b][h][j]
// ---------------------------------------------------------------------------
__global__ __launch_bounds__(512) void proj_mfma3_kernel(
    const float* __restrict__ Q, const float* __restrict__ K, const float* __restrict__ V,
    const unsigned short* __restrict__ Wf,
    float* __restrict__ Qt, float* __restrict__ Kt, unsigned short* __restrict__ VpT)
{
    __shared__ float red[8][64][17];   // +1 pad: lane stride 17 dwords -> all banks

    int gb = blockIdx.x;
    int job = gb >> 8, tile = gb & 255;
    int r0 = tile * 16;
    const float* X = (job == 0) ? Q : (job == 1) ? K : V;
    int ntct  = (job == 2) ? 4 : 2;
    int pbase = job << 6;
    int t = threadIdx.x, w = t >> 6, l = t & 63;
    int lrow = l & 15, lq = l >> 4;

    const float* xrow = &X[(size_t)(r0 + lrow) * DM + w * 128 + lq * 8];

    floatx4 acc[4];
    #pragma unroll
    for (int i = 0; i < 4; ++i) acc[i] = (floatx4){0.f, 0.f, 0.f, 0.f};

    if (job < 2) proj_core<2>(xrow, Wf, pbase, w * 4, l, acc);
    else         proj_core<4>(xrow, Wf, pbase, w * 4, l, acc);

    #pragma unroll
    for (int ct = 0; ct < 4; ++ct) {
        if (ct >= ntct) break;
        #pragma unroll
        for (int r = 0; r < 4; ++r) red[w][l][ct * 4 + r] = acc[ct][r];
    }
    __syncthreads();

    // waves 0..3: wave w sums acc-register r = w across the 8 k-slices.
    // C/D layout: (lane, reg r) -> row r0 + (l>>4)*4 + r, col ct*16 + (l&15).
    if (w < 4) {
        int row = r0 + lq * 4 + w;
        if (job < 2) {
            float* Y = (job == 0) ? Qt : Kt;
            #pragma unroll
            for (int ct = 0; ct < 2; ++ct) {
                float v = 0.f;
                #pragma unroll
                for (int s = 0; s < 8; ++s) v += red[s][l][ct * 4 + w];
                Y[(size_t)row * MBITS + ct * 16 + lrow] = v;
            }
        } else {
            int b = row >> 11, j = row & 2047;
            #pragma unroll
            for (int ct = 0; ct < 4; ++ct) {
                float v = 0.f;
                #pragma unroll
                for (int s = 0; s < 8; ++s) v += red[s][l][ct * 4 + w];
                VpT[(size_t)b * (DH * NB) + (size_t)(ct * 16 + lrow) * NB + j] = f32_to_bf16(v);
            }
        }
    }
}

// ---------------------------------------------------------------------------
// Pass 1: tropical min-plus -> per-(row, j-chunk) partial expsums.
// grid (128, 8, 2) x 256. Block = 16 rows x 256 j, thread 4i x 4j.
// LDS: Qs[16][32] (broadcast reads) + Ks[256][32] XOR-swizzled (conflict-free
// b128). ~34 KB -> 4 blocks/CU.
// ---------------------------------------------------------------------------
__global__ __launch_bounds__(256) void trop_sum_kernel(
    const float* __restrict__ Qt, const float* __restrict__ Kt,
    const float* __restrict__ temp, float* __restrict__ partial)
{
    __shared__ float Qs[16][32];
    __shared__ float Ks[256][32];   // chunk c of row j stored at c ^ (j&7)

    int b  = blockIdx.z;
    int jc = blockIdx.y;
    int i0 = blockIdx.x * 16;
    int t  = threadIdx.x;
    int w  = t >> 6, l = t & 63;

    if (t < 128) {
        int row = t >> 3, c4 = t & 7;
        *(floatx4*)&Qs[row][c4 * 4] =
            *(const floatx4*)&Qt[(size_t)(b * NB + i0 + row) * MBITS + c4 * 4];
    }
    #pragma unroll
    for (int u = 0; u < 8; ++u) {
        int flat4 = u * 256 + t;
        int row = flat4 >> 3, c4 = flat4 & 7;
        *(floatx4*)&Ks[row][(c4 ^ (row & 7)) * 4] =
            *(const floatx4*)&Kt[(size_t)(b * NB + jc * 256 + row) * MBITS + c4 * 4];
    }
    float tv = temp[0];
    float c2 = -(1.0f / log1pf(__expf(tv))) * 1.44269504088896340736f;
    __syncthreads();

    float m[4][4];
    #pragma unroll
    for (int ii = 0; ii < 4; ++ii)
        #pragma unroll
        for (int jj = 0; jj < 4; ++jj) m[ii][jj] = 1e30f;

    int swz = l & 7;
    #pragma unroll
    for (int k4 = 0; k4 < 8; ++k4) {
        floatx4 q[4], kk[4];
        #pragma unroll
        for (int ii = 0; ii < 4; ++ii) q[ii] = *(const floatx4*)&Qs[w + 4 * ii][k4 * 4];
        #pragma unroll
        for (int jj = 0; jj < 4; ++jj)
            kk[jj] = *(const floatx4*)&Ks[l + 64 * jj][(k4 ^ swz) * 4];
        #pragma unroll
        for (int ii = 0; ii < 4; ++ii)
            #pragma unroll
            for (int jj = 0; jj < 4; ++jj) {
                floatx4 av = q[ii] + kk[jj];          // v_pk_add_f32
                m[ii][jj] = fminf(fminf(fminf(fminf(m[ii][jj], av.x), av.y), av.z), av.w);
            }
    }

    #pragma unroll
    for (int ii = 0; ii < 4; ++ii) {
        float s = exp2f(c2 * m[ii][0]) + exp2f(c2 * m[ii][1])
                + exp2f(c2 * m[ii][2]) + exp2f(c2 * m[ii][3]);
        #pragma unroll
        for (int off = 1; off < 64; off <<= 1) s += __shfl_xor(s, off, 64);
        if (l == 0) partial[((size_t)b * NB + i0 + w + 4 * ii) * 8 + jc] = s;
    }
}

// ---------------------------------------------------------------------------
// Pass 2 (fused): recompute tropical, write normalized attn, MFMA partial-out
// (no atomics). grid (128, 8, 2) x 256. Es aliases Ks after a barrier.
// LDS ~34.3 KB -> 4 blocks/CU. B-frags direct from global VpT (L2-resident).
// ---------------------------------------------------------------------------
__global__ __launch_bounds__(256) void trop_fused_kernel(
    const float* __restrict__ Qt, const float* __restrict__ Kt,
    const unsigned short* __restrict__ VpT,
    const float* __restrict__ temp, const float* __restrict__ partial,
    float* __restrict__ po, float* __restrict__ attn)
{
    __shared__ float Qs[16][32];
    __shared__ float Ks[256][32];            // reused as Es after min-loop
    __shared__ float inv_s[16];
    unsigned short (*Es)[264] = (unsigned short (*)[264])&Ks[0][0];  // 8.4 KB

    int b  = blockIdx.z;
    int jc = blockIdx.y;
    int i0 = blockIdx.x * 16;
    int t  = threadIdx.x;
    int w  = t >> 6, l = t & 63;

    if (t < 128) {
        int row = t >> 3, c4 = t & 7;
        *(floatx4*)&Qs[row][c4 * 4] =
            *(const floatx4*)&Qt[(size_t)(b * NB + i0 + row) * MBITS + c4 * 4];
    }
    #pragma unroll
    for (int u = 0; u < 8; ++u) {
        int flat4 = u * 256 + t;
        int row = flat4 >> 3, c4 = flat4 & 7;
        *(floatx4*)&Ks[row][(c4 ^ (row & 7)) * 4] =
            *(const floatx4*)&Kt[(size_t)(b * NB + jc * 256 + row) * MBITS + c4 * 4];
    }
    if (t < 16) {
        float s = 0.f;
        #pragma unroll
        for (int p = 0; p < 8; ++p) s += partial[((size_t)b * NB + i0 + t) * 8 + p];
        inv_s[t] = 1.0f / s;
    }
    float tv = temp[0];
    float c2 = -(1.0f / log1pf(__expf(tv))) * 1.44269504088896340736f;
    __syncthreads();

    float m[4][4];
    #pragma unroll
    for (int ii = 0; ii < 4; ++ii)
        #pragma unroll
        for (int jj = 0; jj < 4; ++jj) m[ii][jj] = 1e30f;

    int swz = l & 7;
    #pragma unroll
    for (int k4 = 0; k4 < 8; ++k4) {
        floatx4 q[4], kk[4];
        #pragma unroll
        for (int ii = 0; ii < 4; ++ii) q[ii] = *(const floatx4*)&Qs[w + 4 * ii][k4 * 4];
        #pragma unroll
        for (int jj = 0; jj < 4; ++jj)
            kk[jj] = *(const floatx4*)&Ks[l + 64 * jj][(k4 ^ swz) * 4];
        #pragma unroll
        for (int ii = 0; ii < 4; ++ii)
            #pragma unroll
            for (int jj = 0; jj < 4; ++jj) {
                floatx4 av = q[ii] + kk[jj];
                m[ii][jj] = fminf(fminf(fminf(fminf(m[ii][jj], av.x), av.y), av.z), av.w);
            }
    }
    __syncthreads();   // all Ks reads done: Es may now overwrite the region

    // e = exp2(c2*m): write normalized attn (coalesced), stage bf16 e in LDS
    #pragma unroll
    for (int ii = 0; ii < 4; ++ii) {
        int i = w + 4 * ii;
        float iv = inv_s[i];
        #pragma unroll
        for (int jj = 0; jj < 4; ++jj) {
            int j = l + 64 * jj;
            float e = exp2f(c2 * m[ii][jj]);
            attn[(size_t)(b * NB + i0 + i) * 2048 + jc * 256 + j] = e * iv;
            Es[i][j] = f32_to_bf16(e);
        }
    }
    __syncthreads();

    // out_partial += Es (A) x VpT-frags (B, direct from global, L2-resident)
    const unsigned short* vb =
        &VpT[(size_t)b * (DH * NB) + (size_t)(w * 16 + (l & 15)) * NB
             + jc * 256 + (l >> 4) * 8];
    floatx4 acc = {0.f, 0.f, 0.f, 0.f};
    #pragma unroll
    for (int kk = 0; kk < 8; ++kk) {
        int mrow = l & 15, q4 = l >> 4;
        shortx8 a  = *(const shortx8*)&Es[mrow][kk * 32 + q4 * 8];
        shortx8 bf = *(const shortx8*)(vb + kk * 32);
        acc = __builtin_amdgcn_mfma_f32_16x16x32_bf16(a, bf, acc, 0, 0, 0);
    }

    // C/D: col=lane&15 (h), row=(lane>>4)*4+reg (i). Deterministic partial
    // store: po[jc][b][i][h] (normalized).
    #pragma unroll
    for (int r = 0; r < 4; ++r) {
        int irow = (l >> 4) * 4 + r;
        po[(size_t)jc * 262144 + (size_t)(b * NB + i0 + irow) * DH + w * 16 + (l & 15)] =
            acc[r] * inv_s[irow];
    }
}

// ---------------------------------------------------------------------------
// Reduce the 8 jc-slices of partial-out into d_out. grid 256 x 256.
// ---------------------------------------------------------------------------
__global__ __launch_bounds__(256) void out_reduce_kernel(
    const float* __restrict__ po, float* __restrict__ outp)
{
    int idx4 = (blockIdx.x * 256 + threadIdx.x) * 4;   // over 262144 floats
    floatx4 a = {0.f, 0.f, 0.f, 0.f};
    #pragma unroll
    for (int jc = 0; jc < 8; ++jc)
        a += *(const floatx4*)&po[(size_t)jc * 262144 + idx4];
    *(floatx4*)&outp[idx4] = a;
}

// ---------------------------------------------------------------------------
extern "C" void kernel_launch(void* const* d_in, const int* in_sizes, int n_in,
                              void* d_out, int out_size, void* d_ws, size_t ws_size,
                              hipStream_t stream) {
    (void)in_sizes; (void)n_in; (void)out_size; (void)ws_size;
    const float* Q    = (const float*)d_in[0];
    const float* K    = (const float*)d_in[1];
    const float* V    = (const float*)d_in[2];
    const float* Wq   = (const float*)d_in[3];
    const float* Wk   = (const float*)d_in[4];
    const float* Wv   = (const float*)d_in[5];
    const float* temp = (const float*)d_in[6];

    float* outp = (float*)d_out;                 // [2][2048][64]
    float* attn = outp + 2 * 2048 * 64;          // [2][2048][2048]

    char* ws = (char*)d_ws;
    float*          Qt      = (float*)(ws);                       // 512 KB
    float*          Kt      = (float*)(ws + 524288);              // 512 KB
    float*          partial = (float*)(ws + 1048576);             // 128 KB
    unsigned short* Wf      = (unsigned short*)(ws + 1179648);    // 512 KB
    unsigned short* VpT     = (unsigned short*)(ws + 1703936);    // 512 KB
    float*          po      = (float*)(ws + 2228224);             // 8 MB partial-out

    wprep_kernel<<<64, 256, 0, stream>>>(Wq, Wk, Wv, Wf);
    proj_mfma3_kernel<<<768, 512, 0, stream>>>(Q, K, V, Wf, Qt, Kt, VpT);
    trop_sum_kernel<<<dim3(128, 8, 2), 256, 0, stream>>>(Qt, Kt, temp, partial);
    trop_fused_kernel<<<dim3(128, 8, 2), 256, 0, stream>>>(
        Qt, Kt, VpT, temp, partial, po, attn);
    out_reduce_kernel<<<256, 256, 0, stream>>>(po, outp);
}